// Round 6
// baseline (154.599 us; speedup 1.0000x reference)
//
#include <hip/hip_runtime.h>
#include <math.h>

// CellSegmentationLoss: fused focal + dice + boundary-BCE + IoU-aux loss.
// Inputs: d_in[0]=pred_masks (16*1*1024*1024 f32), d_in[1]=gt_masks (same),
//         d_in[2]=pred_iou (16 f32). Output: 1 f32 scalar.
//
// R9: R8's non-spilling rolled loop x 2x occupancy.
// Ledger:
//   R3 (46us): 16-load burst, VGPR=60, occ 30%.
//   R4 (56us): 2048px micro-blocks: residency ok, per-block overhead.
//   R5/R6/R7 (124-288us): any fully-unrolled load stream hoists 128+ live
//       VGPRs and SPILLS (WRITE_SIZE 157-194 MB). Never full-unroll this.
//   R8 (50us): rolled 4-load body, VGPR=36, ZERO spill -- and the L3-warm
//       bench passes (hbm_bytes=32KB!) ran the SAME 50us as the HBM-cold
//       pass => NOT bandwidth-bound; stall/latency-bound at occ 28.7%.
// Fix: the 36-VGPR body fits the 64-VGPR cap, so occupancy-8 is finally
// reachable WITHOUT spilling: 2048 blocks (8/CU, one generation),
// bounds(256,8), body unchanged. 2x resident waves -> 2x stall coverage.

#define HW_PIX (1024 * 1024)
#define BATCH 16
constexpr int THREADS = 256;
constexpr int BLOCKS = 2048;                            // 8 / CU, 1 generation
constexpr int BLOCKS_PER_IMG = BLOCKS / BATCH;          // 128
constexpr int PIX_PER_BLOCK = HW_PIX / BLOCKS_PER_IMG;  // 8192
constexpr int F4_PER_THREAD = PIX_PER_BLOCK / (THREADS * 4);  // 8
constexpr int LOOP_ITERS = F4_PER_THREAD / 2;           // 4 (2 f4/array/iter)

struct Accum {
  float fsum, csum, isum, psum;
  float tcnt, bicnt, bpcnt;   // counts as floats: exact for <=2^24
};

__device__ __forceinline__ void process4(const float4 xv, const float4 tv,
                                         Accum& a) {
  const float* xs = reinterpret_cast<const float*>(&xv);
  const float* ts = reinterpret_cast<const float*>(&tv);
#pragma unroll
  for (int j = 0; j < 4; ++j) {
    const float xx = xs[j];
    const float tt = ts[j];
    const float e = __expf(-fabsf(xx));                // exp(-|x|) in (0,1]
    const float s = 1.0f + e;
    const float r = __builtin_amdgcn_rcpf(s);
    const float p = (xx >= 0.0f) ? r : e * r;          // sigmoid(x)
    const float ce = fmaxf(xx, 0.0f) - xx * tt + __logf(s);
    const float om = fmaf(tt, 1.0f - 2.0f * p, p);     // 1 - p_t
    const float at = 0.75f - 0.5f * tt;                // alpha_t
    a.fsum += at * ce * om * om;
    a.csum += ce;
    a.isum = fmaf(p, tt, a.isum);
    a.psum += p;
    const float pb = (xx > 0.0f) ? 1.0f : 0.0f;        // p>0.5 <=> x>0
    a.tcnt += tt;                                      // tt in {0,1}
    a.bpcnt += pb;
    a.bicnt += pb * tt;
  }
}

__global__ __launch_bounds__(THREADS, 8) void
loss_partial(const float* __restrict__ x, const float* __restrict__ t,
             float* __restrict__ acc) {
  const int b = blockIdx.x / BLOCKS_PER_IMG;
  const long base = (long)blockIdx.x * PIX_PER_BLOCK;
  const float4* __restrict__ x4 = (const float4*)(x + base);
  const float4* __restrict__ t4 = (const float4*)(t + base);
  const int tid = threadIdx.x;

  Accum a = {0.f, 0.f, 0.f, 0.f, 0.f, 0.f, 0.f};

  // ROLLED loop: 4 dwordx4 loads per body, bounded footprint (R8: VGPR=36,
  // zero spill). Do NOT full-unroll (R5/R6/R7) or hand-prefetch (R5).
#pragma unroll 1
  for (int i = 0; i < LOOP_ITERS; ++i) {
    const float4 x0 = x4[tid + (2 * i + 0) * THREADS];
    const float4 t0 = t4[tid + (2 * i + 0) * THREADS];
    const float4 x1 = x4[tid + (2 * i + 1) * THREADS];
    const float4 t1 = t4[tid + (2 * i + 1) * THREADS];
    process4(x0, t0, a);
    process4(x1, t1, a);
  }

  __shared__ float red[THREADS / 64][7];
  const int lane = threadIdx.x & 63;
  const int wave = threadIdx.x >> 6;
  const float vals[7] = {a.fsum, a.csum, a.isum, a.psum,
                         a.tcnt, a.bicnt, a.bpcnt};
#pragma unroll
  for (int k = 0; k < 7; ++k) {
    float v = vals[k];
#pragma unroll
    for (int off = 32; off > 0; off >>= 1) v += __shfl_down(v, off);
    if (lane == 0) red[wave][k] = v;
  }
  __syncthreads();
  if (threadIdx.x < 7) {
    const float s = red[0][threadIdx.x] + red[1][threadIdx.x] +
                    red[2][threadIdx.x] + red[3][threadIdx.x];
    atomicAdd(&acc[b * 16 + threadIdx.x], s);  // stride 16: own line/image
  }
}

__global__ void loss_final(const float* __restrict__ acc,
                           const float* __restrict__ pred_iou,
                           float* __restrict__ out) {
  constexpr float SMOOTH = 1e-6f;
  const int lane = threadIdx.x;  // one wave (64), lanes 0..15 active
  float F = 0.f, C = 0.f, D = 0.f, Q = 0.f;
  if (lane < BATCH) {
    const float* a = acc + lane * 16;
    F = a[0];
    C = a[1];
    const float I = a[2], P = a[3], T = a[4], BI = a[5], BP = a[6];
    D = (2.0f * I + SMOOTH) / (P + T + SMOOTH);            // dice term
    const float iou = (BI + SMOOTH) / (BP + T - BI + SMOOTH);
    const float d = pred_iou[lane] - iou;
    Q = d * d;
  }
#pragma unroll
  for (int off = 32; off > 0; off >>= 1) {
    F += __shfl_down(F, off);
    C += __shfl_down(C, off);
    D += __shfl_down(D, off);
    Q += __shfl_down(Q, off);
  }
  if (lane == 0) {
    const float invN = 1.0f / (float)((long)BATCH * HW_PIX);
    const float focal = F * invN;
    const float dice = 1.0f - D * (1.0f / (float)BATCH);
    const float half_boundary = C * invN;  // 0.5 * (2.0 * mean(ce))
    const float iou_loss = Q * (1.0f / (float)BATCH);
    out[0] = focal + dice + half_boundary + 0.1f * iou_loss;
  }
}

extern "C" void kernel_launch(void* const* d_in, const int* in_sizes, int n_in,
                              void* d_out, int out_size, void* d_ws,
                              size_t ws_size, hipStream_t stream) {
  const float* x = (const float*)d_in[0];
  const float* t = (const float*)d_in[1];
  const float* piou = (const float*)d_in[2];
  float* acc = (float*)d_ws;  // BATCH*16 floats

  hipMemsetAsync(acc, 0, BATCH * 16 * sizeof(float), stream);
  loss_partial<<<BLOCKS, THREADS, 0, stream>>>(x, t, acc);
  loss_final<<<1, 64, 0, stream>>>(acc, piou, (float*)d_out);
}